// Round 11
// baseline (4038.103 us; speedup 1.0000x reference)
//
#include <hip/hip_runtime.h>

#define N_NODES 50000
#define N_EDGES 800000
#define HID 64
#define LAYERS 4
#define GRID 1280            // 5 blocks/CU launched; __launch_bounds__(256,6) guarantees
                             // capacity 6/CU (1536) > 1280 -> all blocks co-resident.
#define NPB 40               // ep nodes per block (1280*40 = 51200 >= 50000)
#define EP_CAP 2048          // staged srcS capacity (avg block load ~625)
#define NTILES 782           // 64-row MFMA tiles
#define SCAN_NBLK 25

typedef unsigned short u16;
typedef __attribute__((ext_vector_type(8))) __bf16 bf16x8;
typedef __attribute__((ext_vector_type(8))) unsigned short u16x8;
typedef __attribute__((ext_vector_type(4))) float f32x4;

__device__ __forceinline__ u16 f2bf(float f) {
  unsigned u = __builtin_bit_cast(unsigned, f);
  u += 0x7fffu + ((u >> 16) & 1u);   // RNE
  return (u16)(u >> 16);
}
__device__ __forceinline__ float bf2f(u16 s) {
  return __builtin_bit_cast(float, ((unsigned)s) << 16);
}

// sense-reversing grid barrier; bar[0]=count, bar[1]=generation (zeroed pre-launch)
__device__ __forceinline__ void gbar(int* bar) {
  __syncthreads();
  if (threadIdx.x == 0) {
    __threadfence();
    int g = __hip_atomic_load(bar + 1, __ATOMIC_RELAXED, __HIP_MEMORY_SCOPE_AGENT);
    int a = __hip_atomic_fetch_add(bar, 1, __ATOMIC_ACQ_REL, __HIP_MEMORY_SCOPE_AGENT);
    if (a == GRID - 1) {
      __hip_atomic_store(bar, 0, __ATOMIC_RELAXED, __HIP_MEMORY_SCOPE_AGENT);
      __hip_atomic_store(bar + 1, g + 1, __ATOMIC_RELEASE, __HIP_MEMORY_SCOPE_AGENT);
    } else {
      while (__hip_atomic_load(bar + 1, __ATOMIC_ACQUIRE, __HIP_MEMORY_SCOPE_AGENT) == g)
        __builtin_amdgcn_s_sleep(8);
    }
    __threadfence();
  }
  __syncthreads();
}

__global__ __launch_bounds__(256, 6) void gno_kernel(
    const float* __restrict__ node_pos, const float* __restrict__ node_feat,
    const int* __restrict__ edge_index,
    const float* __restrict__ enc_w, const float* __restrict__ enc_b,
    const float* __restrict__ edge_enc_w, const float* __restrict__ edge_enc_b,
    const float* __restrict__ ew1, const float* __restrict__ eb1,
    const float* __restrict__ ew2, const float* __restrict__ eb2,
    const float* __restrict__ nw1, const float* __restrict__ nb1,
    const float* __restrict__ nw2, const float* __restrict__ nb2,
    const float* __restrict__ dec_w, const float* __restrict__ dec_b,
    float* __restrict__ out,
    u16* __restrict__ h, u16* __restrict__ SA, u16* __restrict__ SB,
    u16* __restrict__ Uarr, u16* __restrict__ aggH,
    u16* __restrict__ W1abT, float* __restrict__ Wvx, float* __restrict__ b1x,
    u16* __restrict__ NB1T, float* __restrict__ bb2, u16* __restrict__ M2T,
    int* __restrict__ cnt, int* __restrict__ offs, int* __restrict__ partials,
    int* __restrict__ rank, int* __restrict__ srcS64, int* __restrict__ bar) {
  __shared__ __align__(16) char smem[11520];
  const int b = blockIdx.x;
  const int t = threadIdx.x;
  const int tid = b * 256 + t;
  const int T = GRID * 256;
  const int lane = t & 63, wvi = t >> 6;
  const int n16 = lane & 15, quad = lane >> 4;
  const int F = wvi * 16;
  const int* dstA = edge_index + N_EDGES;

  // ================= P0: zero cnt, prep weights, encode h ===================
  for (int i = tid; i < N_NODES; i += T) cnt[i] = 0;
  {
    const int szA = LAYERS * 128 * 64, szV = LAYERS * 3 * 64, szB = LAYERS * 64;
    const int szN = LAYERS * 64 * 128, szb2 = LAYERS * 64, szM = LAYERS * 64 * 64;
    const int tot = szA + szV + szB + szN + szb2 + szM;
    for (int i = tid; i < tot; i += T) {
      int idx = i;
      if (idx < szA) {
        int l = idx / (128 * 64); int r = idx % (128 * 64);
        int nf = r / 64; int k = r % 64;
        int half = nf >> 6, f = nf & 63;
        W1abT[idx] = f2bf(ew1[(l * 192 + half * 64 + k) * 64 + f]);
        continue;
      }
      idx -= szA;
      if (idx < szV) {
        int l = idx / 192, r = idx % 192, a = r / 64, f = r % 64;
        float s = 0.f;
        for (int m = 0; m < 64; ++m) s += edge_enc_w[a * 64 + m] * ew1[(l * 192 + 128 + m) * 64 + f];
        Wvx[idx] = s;
        continue;
      }
      idx -= szV;
      if (idx < szB) {
        int l = idx / 64, f = idx % 64;
        float s = eb1[l * 64 + f];
        for (int m = 0; m < 64; ++m) s += edge_enc_b[m] * ew1[(l * 192 + 128 + m) * 64 + f];
        b1x[idx] = s;
        continue;
      }
      idx -= szB;
      if (idx < szN) {
        int l = idx / 8192, r = idx % 8192, f = r / 128, k = r % 128;
        float v;
        if (k < 64) v = nw1[(l * 128 + k) * 64 + f];
        else {
          int j = k - 64; float s = 0.f;
          for (int g = 0; g < 64; ++g)
            s += ew2[(l * 64 + j) * 64 + g] * nw1[(l * 128 + 64 + g) * 64 + f];
          v = s;
        }
        NB1T[idx] = f2bf(v);
        continue;
      }
      idx -= szN;
      if (idx < szb2) {
        int l = idx / 64, f = idx % 64;
        float s = 0.f;
        for (int g = 0; g < 64; ++g) s += eb2[l * 64 + g] * nw1[(l * 128 + 64 + g) * 64 + f];
        bb2[idx] = s;
        continue;
      }
      idx -= szb2;
      int l = idx / 4096, r = idx % 4096, f = r / 64, k = r % 64;
      M2T[idx] = f2bf(nw2[(l * 64 + k) * 64 + f]);
    }
  }
  for (int i = tid; i < N_NODES * HID; i += T) {
    int n = i >> 6, j = i & 63;
    float s = enc_b[j]
            + node_feat[n * 3 + 0] * enc_w[j]
            + node_feat[n * 3 + 1] * enc_w[64 + j]
            + node_feat[n * 3 + 2] * enc_w[128 + j];
    h[i] = f2bf(s);
  }
  gbar(bar);

  // ================= P1: histogram + rank ====================================
  for (int i = tid; i < N_EDGES; i += T)
    rank[i] = atomicAdd(&cnt[dstA[i]], 1);
  gbar(bar);

  // ================= P2: scan1 (blocks 0..24) || su layer 0 (blocks 25..806) =
  if (b < SCAN_NBLK) {
    int* sm = (int*)smem;
    int* ws2 = (int*)(smem + 8192);
    int base = b * 2048;
#pragma unroll
    for (int i = 0; i < 8; ++i) {
      int idx = base + i * 256 + t;
      sm[i * 256 + t] = (idx < N_NODES) ? cnt[idx] : 0;
    }
    __syncthreads();
    int loc[8]; int s = 0;
#pragma unroll
    for (int i = 0; i < 8; ++i) { loc[i] = s; s += sm[t * 8 + i]; }
    ws2[t] = s;
    __syncthreads();
    for (int off = 1; off < 256; off <<= 1) {
      int u = (t >= off) ? ws2[t - off] : 0;
      __syncthreads();
      ws2[t] += u;
      __syncthreads();
    }
    int tbase = (t > 0) ? ws2[t - 1] : 0;
    if (t == 255) partials[b] = ws2[255];
#pragma unroll
    for (int i = 0; i < 8; ++i) {
      int idx = base + t * 8 + i;
      if (idx < N_NODES) offs[idx] = tbase + loc[i];
    }
  } else if (b < SCAN_NBLK + NTILES) {
    // su: S'(0) = h@W1a - pos.Wv(0); U'(0) = h@W1b + pos.Wv(0) + b1(0)
    float* sPos = (float*)smem;
    int n0 = (b - SCAN_NBLK) * 64;
    if (t < 192) {
      int idx = n0 * 3 + t;
      sPos[t] = (idx < N_NODES * 3) ? node_pos[idx] : 0.f;
    }
    __syncthreads();
    bf16x8 B[2][2];
    float w0[2], w1[2], w2[2], bb[2]; bool isU[2];
#pragma unroll
    for (int nt = 0; nt < 2; ++nt) {
      int col = wvi * 32 + nt * 16 + n16;
      const u16* p = W1abT + (size_t)col * 64 + quad * 8;
      B[nt][0] = __builtin_bit_cast(bf16x8, *(const u16x8*)(p));
      B[nt][1] = __builtin_bit_cast(bf16x8, *(const u16x8*)(p + 32));
      int f = col & 63; isU[nt] = col >= 64;
      w0[nt] = Wvx[0 * 64 + f];
      w1[nt] = Wvx[1 * 64 + f];
      w2[nt] = Wvx[2 * 64 + f];
      bb[nt] = b1x[f];
    }
    f32x4 acc[4][2];
#pragma unroll
    for (int m = 0; m < 4; ++m)
#pragma unroll
      for (int nt = 0; nt < 2; ++nt) acc[m][nt] = (f32x4){0.f, 0.f, 0.f, 0.f};
#pragma unroll
    for (int m = 0; m < 4; ++m) {
      int row = n0 + m * 16 + n16;
      if (row >= N_NODES) row = N_NODES - 1;
      const u16* hp = h + (size_t)row * 64 + quad * 8;
      bf16x8 a0 = __builtin_bit_cast(bf16x8, *(const u16x8*)(hp));
      bf16x8 a1 = __builtin_bit_cast(bf16x8, *(const u16x8*)(hp + 32));
#pragma unroll
      for (int nt = 0; nt < 2; ++nt) {
        acc[m][nt] = __builtin_amdgcn_mfma_f32_16x16x32_bf16(a0, B[nt][0], acc[m][nt], 0, 0, 0);
        acc[m][nt] = __builtin_amdgcn_mfma_f32_16x16x32_bf16(a1, B[nt][1], acc[m][nt], 0, 0, 0);
      }
    }
#pragma unroll
    for (int m = 0; m < 4; ++m)
#pragma unroll
      for (int nt = 0; nt < 2; ++nt) {
        int col = wvi * 32 + nt * 16 + n16;
        int f = col & 63;
#pragma unroll
        for (int r = 0; r < 4; ++r) {
          int e = m * 16 + quad * 4 + r;
          int grow = n0 + e;
          if (grow < N_NODES) {
            float P = sPos[e * 3] * w0[nt] + sPos[e * 3 + 1] * w1[nt] + sPos[e * 3 + 2] * w2[nt];
            if (!isU[nt]) SA[(size_t)grow * 64 + f] = f2bf(acc[m][nt][r] - P);
            else          Uarr[(size_t)grow * 64 + f] = f2bf(acc[m][nt][r] + P + bb[nt]);
          }
        }
      }
  }
  gbar(bar);

  // ================= P3: add scan partial prefixes ===========================
  for (int i = tid; i < N_NODES; i += T) {
    int blk = i >> 11;
    int s = 0;
    for (int k = 0; k < blk; ++k) s += partials[k];
    offs[i] += s;
  }
  gbar(bar);

  // ================= P4: scatter (atomic-free; src premultiplied by 64) ======
  for (int i = tid; i < N_EDGES; i += T) {
    int s = edge_index[i], d = dstA[i];
    srcS64[offs[d] + rank[i]] = s << 6;
  }
  gbar(bar);

  // ================= layers ==================================================
  for (int l = 0; l < LAYERS; ++l) {
    const u16* Sread = (l & 1) ? SB : SA;
    u16* Swrite = (l & 1) ? SA : SB;

    // ---- ep: aggH[d] = sum_e relu(S'[src] + U'[d]) ; LDS-staged indices ----
    {
      int* sIdx = (int*)smem;
      int* sOff = (int*)(smem + 8192);
      int d0b = b * NPB;
      if (t <= NPB) {
        int d = d0b + t;
        sOff[t] = (d < N_NODES) ? offs[d] : N_EDGES;
      }
      __syncthreads();
      int eS = sOff[0];
      int nE = sOff[NPB] - eS;
      bool fit = (nE <= EP_CAP);
      if (fit) {
        for (int i = t; i < nE; i += 256) sIdx[i] = srcS64[eS + i];
      }
      __syncthreads();
      int f = lane;
      for (int i = 0; i < NPB / 4; ++i) {
        int nl = wvi * (NPB / 4) + i;
        int d = d0b + nl;
        if (d >= N_NODES) break;
        int e0 = sOff[nl];
        int deg = sOff[nl + 1] - e0;
        float Ub = bf2f(Uarr[(size_t)d * 64 + f]);
        float sum = 0.f;
        int full = deg & ~7;
        int base = 0;
        if (fit) {
          int rel = e0 - eS;
          for (; base < full; base += 8) {
            u16 S[8];
#pragma unroll
            for (int k = 0; k < 8; ++k) {
              int s64 = sIdx[rel + base + k];
              S[k] = Sread[(size_t)s64 + f];
            }
#pragma unroll
            for (int k = 0; k < 8; ++k) sum += fmaxf(bf2f(S[k]) + Ub, 0.f);
          }
          if (base < deg) {
            u16 S[8]; bool ok[8];
#pragma unroll
            for (int k = 0; k < 8; ++k) {
              int j = base + k;
              ok[k] = j < deg;
              int s64 = sIdx[rel + (ok[k] ? j : 0)];
              S[k] = Sread[(size_t)s64 + f];
            }
#pragma unroll
            for (int k = 0; k < 8; ++k) {
              float z = fmaxf(bf2f(S[k]) + Ub, 0.f);
              sum += ok[k] ? z : 0.f;
            }
          }
        } else {
          for (; base < full; base += 8) {
            u16 S[8];
#pragma unroll
            for (int k = 0; k < 8; ++k) {
              int s64 = srcS64[e0 + base + k];
              S[k] = Sread[(size_t)s64 + f];
            }
#pragma unroll
            for (int k = 0; k < 8; ++k) sum += fmaxf(bf2f(S[k]) + Ub, 0.f);
          }
          if (base < deg) {
            u16 S[8]; bool ok[8];
#pragma unroll
            for (int k = 0; k < 8; ++k) {
              int j = base + k;
              ok[k] = j < deg;
              int s64 = srcS64[e0 + (ok[k] ? j : 0)];
              S[k] = Sread[(size_t)s64 + f];
            }
#pragma unroll
            for (int k = 0; k < 8; ++k) {
              float z = fmaxf(bf2f(S[k]) + Ub, 0.f);
              sum += ok[k] ? z : 0.f;
            }
          }
        }
        aggH[(size_t)d * 64 + f] = f2bf(sum);
      }
    }
    gbar(bar);

    // ---- node MLP (+ next-layer S'/U' | decoder) on blocks 0..NTILES-1 -----
    if (b < NTILES) {
      u16* Hs = (u16*)smem;                       // 9216 B
      float* sDeg = (float*)(smem + 9216);        // 256 B
      float* sPos = (float*)(smem + 9472);        // 768 B
      float* sRed = (float*)(smem + 10240);       // 1024 B  [64][4]
      int n0 = b * 64;
      if (t < 64) {
        int gn = n0 + t;
        sDeg[t] = (gn < N_NODES) ? (float)cnt[gn] : 0.f;
      }
      if (t >= 64 && t < 256) {
        int i = t - 64;
        int idx = n0 * 3 + i;
        sPos[i] = (idx < N_NODES * 3) ? node_pos[idx] : 0.f;
      }
      bf16x8 B1[4], B2[2];
      {
        const u16* p = NB1T + (size_t)(l * 64 + F + n16) * 128 + quad * 8;
#pragma unroll
        for (int ks = 0; ks < 4; ++ks) B1[ks] = __builtin_bit_cast(bf16x8, *(const u16x8*)(p + ks * 32));
        const u16* q = M2T + (size_t)(l * 64 + F + n16) * 64 + quad * 8;
#pragma unroll
        for (int ks = 0; ks < 2; ++ks) B2[ks] = __builtin_bit_cast(bf16x8, *(const u16x8*)(q + ks * 32));
      }
      float bias1 = nb1[l * 64 + F + n16];
      float bb2f = bb2[l * 64 + F + n16];
      float bias2 = nb2[l * 64 + F + n16];
      __syncthreads();

      // GEMM1: [h|aggH] @ NB1T
      f32x4 acc[4];
#pragma unroll
      for (int m = 0; m < 4; ++m) acc[m] = (f32x4){0.f, 0.f, 0.f, 0.f};
#pragma unroll
      for (int m = 0; m < 4; ++m) {
        int row = n0 + m * 16 + n16;
        if (row >= N_NODES) row = N_NODES - 1;
        const u16* hp = h + (size_t)row * 64 + quad * 8;
        const u16* ap = aggH + (size_t)row * 64 + quad * 8;
        bf16x8 a0 = __builtin_bit_cast(bf16x8, *(const u16x8*)(hp));
        bf16x8 a1 = __builtin_bit_cast(bf16x8, *(const u16x8*)(hp + 32));
        bf16x8 a2 = __builtin_bit_cast(bf16x8, *(const u16x8*)(ap));
        bf16x8 a3 = __builtin_bit_cast(bf16x8, *(const u16x8*)(ap + 32));
        acc[m] = __builtin_amdgcn_mfma_f32_16x16x32_bf16(a0, B1[0], acc[m], 0, 0, 0);
        acc[m] = __builtin_amdgcn_mfma_f32_16x16x32_bf16(a1, B1[1], acc[m], 0, 0, 0);
        acc[m] = __builtin_amdgcn_mfma_f32_16x16x32_bf16(a2, B1[2], acc[m], 0, 0, 0);
        acc[m] = __builtin_amdgcn_mfma_f32_16x16x32_bf16(a3, B1[3], acc[m], 0, 0, 0);
      }
#pragma unroll
      for (int m = 0; m < 4; ++m)
#pragma unroll
        for (int r = 0; r < 4; ++r) {
          int e = m * 16 + quad * 4 + r;
          float v = acc[m][r] + bias1 + sDeg[e] * bb2f;
          v = v > 0.f ? v : 0.f;
          Hs[e * 72 + F + n16] = f2bf(v);
        }
      __syncthreads();

      // GEMM2 -> h2 in registers
      float c2[4][4];
#pragma unroll
      for (int m = 0; m < 4; ++m) {
        const u16* hp = Hs + (m * 16 + n16) * 72 + quad * 8;
        f32x4 c = (f32x4){0.f, 0.f, 0.f, 0.f};
#pragma unroll
        for (int ks = 0; ks < 2; ++ks) {
          bf16x8 a = __builtin_bit_cast(bf16x8, *(const u16x8*)(hp + ks * 32));
          c = __builtin_amdgcn_mfma_f32_16x16x32_bf16(a, B2[ks], c, 0, 0, 0);
        }
#pragma unroll
        for (int r = 0; r < 4; ++r) c2[m][r] = c[r] + bias2;
      }
      __syncthreads();

      // h2 tile -> LDS; h global update (tile-local, in-block ordering)
#pragma unroll
      for (int m = 0; m < 4; ++m)
#pragma unroll
        for (int r = 0; r < 4; ++r) {
          int e = m * 16 + quad * 4 + r;
          u16 hv = f2bf(c2[m][r]);
          Hs[e * 72 + F + n16] = hv;
          int gn = n0 + e;
          if (l < LAYERS - 1 && gn < N_NODES)
            h[(size_t)gn * 64 + F + n16] = hv;
        }
      __syncthreads();

      if (l < LAYERS - 1) {
        int lp = l + 1;
        bf16x8 B3[2][2];
        float w0[2], w1[2], w2[2], bb[2]; bool isU[2];
#pragma unroll
        for (int nt = 0; nt < 2; ++nt) {
          int col = wvi * 32 + nt * 16 + n16;
          const u16* p = W1abT + (size_t)(lp * 128 + col) * 64 + quad * 8;
          B3[nt][0] = __builtin_bit_cast(bf16x8, *(const u16x8*)(p));
          B3[nt][1] = __builtin_bit_cast(bf16x8, *(const u16x8*)(p + 32));
          int f = col & 63; isU[nt] = col >= 64;
          w0[nt] = Wvx[(lp * 3 + 0) * 64 + f];
          w1[nt] = Wvx[(lp * 3 + 1) * 64 + f];
          w2[nt] = Wvx[(lp * 3 + 2) * 64 + f];
          bb[nt] = b1x[lp * 64 + f];
        }
        f32x4 a3[4][2];
#pragma unroll
        for (int m = 0; m < 4; ++m)
#pragma unroll
          for (int nt = 0; nt < 2; ++nt) a3[m][nt] = (f32x4){0.f, 0.f, 0.f, 0.f};
#pragma unroll
        for (int m = 0; m < 4; ++m) {
          const u16* hp = Hs + (m * 16 + n16) * 72 + quad * 8;
          bf16x8 a0 = __builtin_bit_cast(bf16x8, *(const u16x8*)(hp));
          bf16x8 a1 = __builtin_bit_cast(bf16x8, *(const u16x8*)(hp + 32));
#pragma unroll
          for (int nt = 0; nt < 2; ++nt) {
            a3[m][nt] = __builtin_amdgcn_mfma_f32_16x16x32_bf16(a0, B3[nt][0], a3[m][nt], 0, 0, 0);
            a3[m][nt] = __builtin_amdgcn_mfma_f32_16x16x32_bf16(a1, B3[nt][1], a3[m][nt], 0, 0, 0);
          }
        }
#pragma unroll
        for (int m = 0; m < 4; ++m)
#pragma unroll
          for (int nt = 0; nt < 2; ++nt) {
            int col = wvi * 32 + nt * 16 + n16;
            int f = col & 63;
#pragma unroll
            for (int r = 0; r < 4; ++r) {
              int e = m * 16 + quad * 4 + r;
              int grow = n0 + e;
              if (grow < N_NODES) {
                float P = sPos[e * 3] * w0[nt] + sPos[e * 3 + 1] * w1[nt] + sPos[e * 3 + 2] * w2[nt];
                if (!isU[nt]) Swrite[(size_t)grow * 64 + f] = f2bf(a3[m][nt][r] - P);
                else          Uarr[(size_t)grow * 64 + f] = f2bf(a3[m][nt][r] + P + bb[nt]);
              }
            }
          }
      } else {
        // fused decoder
        int e = t >> 2, part = t & 3;
        float s = 0.f;
#pragma unroll
        for (int j = 0; j < 16; ++j)
          s += bf2f(Hs[e * 72 + part * 16 + j]) * dec_w[part * 16 + j];
        sRed[e * 4 + part] = s;
        __syncthreads();
        if (part == 0) {
          int gn = n0 + e;
          if (gn < N_NODES)
            out[gn] = sRed[e * 4] + sRed[e * 4 + 1] + sRed[e * 4 + 2] + sRed[e * 4 + 3] + dec_b[0];
        }
      }
    }
    if (l < LAYERS - 1) gbar(bar);
  }
}

extern "C" void kernel_launch(void* const* d_in, const int* in_sizes, int n_in,
                              void* d_out, int out_size, void* d_ws, size_t ws_size,
                              hipStream_t stream) {
  const float* node_pos   = (const float*)d_in[0];
  const float* node_feat  = (const float*)d_in[1];
  const int*   edge_index = (const int*)d_in[2];
  const float* enc_w      = (const float*)d_in[3];
  const float* enc_b      = (const float*)d_in[4];
  const float* edge_enc_w = (const float*)d_in[5];
  const float* edge_enc_b = (const float*)d_in[6];
  const float* ew1        = (const float*)d_in[7];
  const float* eb1        = (const float*)d_in[8];
  const float* ew2        = (const float*)d_in[9];
  const float* eb2        = (const float*)d_in[10];
  const float* nw1        = (const float*)d_in[11];
  const float* nb1        = (const float*)d_in[12];
  const float* nw2        = (const float*)d_in[13];
  const float* nb2        = (const float*)d_in[14];
  const float* dec_w      = (const float*)d_in[15];
  const float* dec_b      = (const float*)d_in[16];
  float* out = (float*)d_out;

  char* ws = (char*)d_ws;
  size_t off = 0;
  u16*    h     = (u16*)(ws + off);    off += (size_t)N_NODES * 64 * 2;
  u16*    SA    = (u16*)(ws + off);    off += (size_t)N_NODES * 64 * 2;
  u16*    SB    = (u16*)(ws + off);    off += (size_t)N_NODES * 64 * 2;
  u16*    Uarr  = (u16*)(ws + off);    off += (size_t)N_NODES * 64 * 2;
  u16*    aggH  = (u16*)(ws + off);    off += (size_t)N_NODES * 64 * 2;
  u16*    W1abT = (u16*)(ws + off);    off += (size_t)LAYERS * 128 * 64 * 2;
  float*  Wvx   = (float*)(ws + off);  off += (size_t)LAYERS * 3 * 64 * 4;
  float*  b1x   = (float*)(ws + off);  off += (size_t)LAYERS * 64 * 4;
  u16*    NB1T  = (u16*)(ws + off);    off += (size_t)LAYERS * 64 * 128 * 2;
  float*  bb2   = (float*)(ws + off);  off += (size_t)LAYERS * 64 * 4;
  u16*    M2T   = (u16*)(ws + off);    off += (size_t)LAYERS * 64 * 64 * 2;
  int*    cnt      = (int*)(ws + off); off += (size_t)N_NODES * 4;
  int*    offsB    = (int*)(ws + off); off += (size_t)N_NODES * 4;
  int*    partials = (int*)(ws + off); off += 32 * 4;
  int*    rank     = (int*)(ws + off); off += (size_t)N_EDGES * 4;
  int*    srcS64   = (int*)(ws + off); off += (size_t)N_EDGES * 4;
  int*    bar      = (int*)(ws + off); off += 64;

  hipMemsetAsync(bar, 0, 8, stream);
  gno_kernel<<<GRID, 256, 0, stream>>>(
      node_pos, node_feat, edge_index,
      enc_w, enc_b, edge_enc_w, edge_enc_b,
      ew1, eb1, ew2, eb2, nw1, nb1, nw2, nb2, dec_w, dec_b, out,
      h, SA, SB, Uarr, aggH,
      W1abT, Wvx, b1x, NB1T, bb2, M2T,
      cnt, offsB, partials, rank, srcS64, bar);
}

// Round 12
// 345.445 us; speedup vs baseline: 11.6896x; 11.6896x over previous
//
#include <hip/hip_runtime.h>

#define N_NODES 50000
#define N_EDGES 800000
#define HID 64
#define LAYERS 4
#define EP_NPB 28          // nodes per ep block (4 waves x 7)
#define EP_CAP 2048        // staged srcS capacity (avg block load ~450)

typedef unsigned short u16;
typedef __attribute__((ext_vector_type(8))) __bf16 bf16x8;
typedef __attribute__((ext_vector_type(8))) unsigned short u16x8;
typedef __attribute__((ext_vector_type(4))) float f32x4;

__device__ __forceinline__ u16 f2bf(float f) {
  unsigned u = __builtin_bit_cast(unsigned, f);
  u += 0x7fffu + ((u >> 16) & 1u);   // RNE
  return (u16)(u >> 16);
}
__device__ __forceinline__ float bf2f(u16 s) {
  return __builtin_bit_cast(float, ((unsigned)s) << 16);
}

// ---------------- init: zero cnt + weight prep + encoder (one launch) --------
// W1abT: [L][128][64] bf16 — cols 0-63 = W1a (src), 64-127 = W1b (dst), [n][k]
// Wvx:   [L][3][64] f32  (We@W1c folded rank-3 edge_vec term)
// b1x:   [L][64] f32     (b1 + be@W1c)
// NB1T:  [L][64][128] bf16 — node GEMM1 B: k<64 = M1a^T, k>=64 = (W2@M1b)^T
// bb2:   [L][64] f32     (b2@M1b — scaled by deg in node epilogue)
// M2T:   [L][64][64] bf16
__global__ __launch_bounds__(256) void init_kernel(
    const float* __restrict__ nf, const float* __restrict__ enc_w,
    const float* __restrict__ enc_b,
    const float* __restrict__ ew1, const float* __restrict__ eb1,
    const float* __restrict__ ew2, const float* __restrict__ eb2,
    const float* __restrict__ nw1, const float* __restrict__ nw2,
    const float* __restrict__ edge_enc_w, const float* __restrict__ edge_enc_b,
    u16* __restrict__ h, u16* W1abT, float* Wvx, float* b1x,
    u16* NB1T, float* bb2, u16* M2T, int* __restrict__ cnt) {
  const int T = gridDim.x * 256;
  int tid = blockIdx.x * 256 + threadIdx.x;
  for (int i = tid; i < N_NODES; i += T) cnt[i] = 0;
  {
    const int szA = LAYERS * 128 * 64, szV = LAYERS * 3 * 64, szB = LAYERS * 64;
    const int szN = LAYERS * 64 * 128, szb2 = LAYERS * 64, szM = LAYERS * 64 * 64;
    const int tot = szA + szV + szB + szN + szb2 + szM;
    for (int i = tid; i < tot; i += T) {
      int idx = i;
      if (idx < szA) {
        int l = idx / (128 * 64); int r = idx % (128 * 64);
        int nfc = r / 64; int k = r % 64;
        int half = nfc >> 6, f = nfc & 63;
        W1abT[idx] = f2bf(ew1[(l * 192 + half * 64 + k) * 64 + f]);
        continue;
      }
      idx -= szA;
      if (idx < szV) {
        int l = idx / 192, r = idx % 192, a = r / 64, f = r % 64;
        float s = 0.f;
        for (int m = 0; m < 64; ++m) s += edge_enc_w[a * 64 + m] * ew1[(l * 192 + 128 + m) * 64 + f];
        Wvx[idx] = s;
        continue;
      }
      idx -= szV;
      if (idx < szB) {
        int l = idx / 64, f = idx % 64;
        float s = eb1[l * 64 + f];
        for (int m = 0; m < 64; ++m) s += edge_enc_b[m] * ew1[(l * 192 + 128 + m) * 64 + f];
        b1x[idx] = s;
        continue;
      }
      idx -= szB;
      if (idx < szN) {
        int l = idx / 8192, r = idx % 8192, f = r / 128, k = r % 128;
        float v;
        if (k < 64) v = nw1[(l * 128 + k) * 64 + f];
        else {
          int j = k - 64; float s = 0.f;
          for (int g = 0; g < 64; ++g)
            s += ew2[(l * 64 + j) * 64 + g] * nw1[(l * 128 + 64 + g) * 64 + f];
          v = s;
        }
        NB1T[idx] = f2bf(v);
        continue;
      }
      idx -= szN;
      if (idx < szb2) {
        int l = idx / 64, f = idx % 64;
        float s = 0.f;
        for (int g = 0; g < 64; ++g) s += eb2[l * 64 + g] * nw1[(l * 128 + 64 + g) * 64 + f];
        bb2[idx] = s;
        continue;
      }
      idx -= szb2;
      int l = idx / 4096, r = idx % 4096, f = r / 64, k = r % 64;
      M2T[idx] = f2bf(nw2[(l * 64 + k) * 64 + f]);
    }
  }
  for (int i = tid; i < N_NODES * HID; i += T) {
    int n = i >> 6, j = i & 63;
    float s = enc_b[j]
            + nf[n * 3 + 0] * enc_w[j]
            + nf[n * 3 + 1] * enc_w[64 + j]
            + nf[n * 3 + 2] * enc_w[128 + j];
    h[i] = f2bf(s);
  }
}

// ---------------- CSR build: hist (+rank), scan, atomic-free scatter ---------
__global__ __launch_bounds__(256) void hist_kernel(const int* __restrict__ dstA,
                                                   int* __restrict__ cnt,
                                                   int* __restrict__ rank) {
  int idx = blockIdx.x * 256 + threadIdx.x;
  if (idx < N_EDGES) rank[idx] = atomicAdd(&cnt[dstA[idx]], 1);
}

#define SCAN_NBLK 25
__global__ __launch_bounds__(256) void scan1_kernel(const int* __restrict__ cnt,
                                                    int* __restrict__ offs,
                                                    int* __restrict__ partials) {
  __shared__ int sm[2048];
  __shared__ int ws2[256];
  int t = threadIdx.x, b = blockIdx.x;
  int base = b * 2048;
#pragma unroll
  for (int i = 0; i < 8; ++i) {
    int idx = base + i * 256 + t;
    sm[i * 256 + t] = (idx < N_NODES) ? cnt[idx] : 0;
  }
  __syncthreads();
  int loc[8]; int s = 0;
#pragma unroll
  for (int i = 0; i < 8; ++i) { loc[i] = s; s += sm[t * 8 + i]; }
  ws2[t] = s;
  __syncthreads();
  for (int off = 1; off < 256; off <<= 1) {
    int u = (t >= off) ? ws2[t - off] : 0;
    __syncthreads();
    ws2[t] += u;
    __syncthreads();
  }
  int tbase = (t > 0) ? ws2[t - 1] : 0;
  if (t == 255) partials[b] = ws2[255];   // raw block total
#pragma unroll
  for (int i = 0; i < 8; ++i) {
    int idx = base + t * 8 + i;
    if (idx < N_NODES) offs[idx] = tbase + loc[i];
  }
}

// scan3 folds the 25-partial prefix in: each 256-node block belongs to exactly
// one scan1 block (2048-aligned), so the prefix is uniform per block.
__global__ __launch_bounds__(256) void scan3_kernel(int* __restrict__ offs,
                                                    const int* __restrict__ partials) {
  __shared__ int pref;
  int blk = (blockIdx.x * 256) >> 11;
  if (threadIdx.x == 0) {
    int s = 0;
    for (int i = 0; i < blk; ++i) s += partials[i];
    pref = s;
  }
  __syncthreads();
  int idx = blockIdx.x * 256 + threadIdx.x;
  if (idx < N_NODES) offs[idx] += pref;
}

// atomic-free scatter; stores src*64 (premultiplied element offset for ep)
__global__ __launch_bounds__(256) void scatter_kernel(const int* __restrict__ ei,
                                                      const int* __restrict__ offs,
                                                      const int* __restrict__ rank,
                                                      int* __restrict__ srcS64) {
  int idx = blockIdx.x * 256 + threadIdx.x;
  if (idx >= N_EDGES) return;
  int s = ei[idx], d = ei[N_EDGES + idx];
  srcS64[offs[d] + rank[idx]] = s << 6;
}

// ---------------- su (layer 0 only): S' = h@W1a − pos·Wv ; U' = h@W1b + pos·Wv + b1
__global__ __launch_bounds__(256) void su_kernel(const u16* __restrict__ h,
                                                 const u16* __restrict__ W1abT,
                                                 const float* __restrict__ Wvx,
                                                 const float* __restrict__ b1x,
                                                 const float* __restrict__ pos,
                                                 u16* __restrict__ Sarr,
                                                 u16* __restrict__ Uarr, int layer) {
  __shared__ float sPos[192];
  int t = threadIdx.x;
  int lane = t & 63, wvi = t >> 6;
  int n16 = lane & 15, quad = lane >> 4;
  int n0 = blockIdx.x * 64;
  if (t < 192) {
    int idx = n0 * 3 + t;
    sPos[t] = (idx < N_NODES * 3) ? pos[idx] : 0.f;
  }
  __syncthreads();

  bf16x8 B[2][2];
  float w0[2], w1[2], w2[2], bb[2]; bool isU[2];
#pragma unroll
  for (int nt = 0; nt < 2; ++nt) {
    int col = wvi * 32 + nt * 16 + n16;
    const u16* p = W1abT + (size_t)(layer * 128 + col) * 64 + quad * 8;
    B[nt][0] = __builtin_bit_cast(bf16x8, *(const u16x8*)(p));
    B[nt][1] = __builtin_bit_cast(bf16x8, *(const u16x8*)(p + 32));
    int f = col & 63; isU[nt] = col >= 64;
    w0[nt] = Wvx[(layer * 3 + 0) * 64 + f];
    w1[nt] = Wvx[(layer * 3 + 1) * 64 + f];
    w2[nt] = Wvx[(layer * 3 + 2) * 64 + f];
    bb[nt] = b1x[layer * 64 + f];
  }
  f32x4 acc[4][2];
#pragma unroll
  for (int m = 0; m < 4; ++m)
#pragma unroll
    for (int nt = 0; nt < 2; ++nt) acc[m][nt] = (f32x4){0.f, 0.f, 0.f, 0.f};

#pragma unroll
  for (int m = 0; m < 4; ++m) {
    int row = n0 + m * 16 + n16;
    if (row >= N_NODES) row = N_NODES - 1;
    const u16* hp = h + (size_t)row * 64 + quad * 8;
    bf16x8 a0 = __builtin_bit_cast(bf16x8, *(const u16x8*)(hp));
    bf16x8 a1 = __builtin_bit_cast(bf16x8, *(const u16x8*)(hp + 32));
#pragma unroll
    for (int nt = 0; nt < 2; ++nt) {
      acc[m][nt] = __builtin_amdgcn_mfma_f32_16x16x32_bf16(a0, B[nt][0], acc[m][nt], 0, 0, 0);
      acc[m][nt] = __builtin_amdgcn_mfma_f32_16x16x32_bf16(a1, B[nt][1], acc[m][nt], 0, 0, 0);
    }
  }
#pragma unroll
  for (int m = 0; m < 4; ++m)
#pragma unroll
    for (int nt = 0; nt < 2; ++nt) {
      int col = wvi * 32 + nt * 16 + n16;
      int f = col & 63;
#pragma unroll
      for (int r = 0; r < 4; ++r) {
        int e = m * 16 + quad * 4 + r;
        int grow = n0 + e;
        if (grow < N_NODES) {
          float P = sPos[e * 3] * w0[nt] + sPos[e * 3 + 1] * w1[nt] + sPos[e * 3 + 2] * w2[nt];
          if (!isU[nt]) Sarr[(size_t)grow * 64 + f] = f2bf(acc[m][nt][r] - P);
          else          Uarr[(size_t)grow * 64 + f] = f2bf(acc[m][nt][r] + P + bb[nt]);
        }
      }
    }
}

// ---------------- edge pass: aggH[d] = sum_e relu(S'[src] + U'[d]) -----------
// Block-cooperative LDS staging of the block's contiguous srcS slice kills the
// srcS->gather dependent chain; gathers issue back-to-back off LDS indices.
__global__ __launch_bounds__(256) void ep_kernel(const u16* __restrict__ Sarr,
                                                 const u16* __restrict__ Uarr,
                                                 const int* __restrict__ srcS64,
                                                 const int* __restrict__ offs,
                                                 u16* __restrict__ aggH) {
  __shared__ int sIdx[EP_CAP];
  __shared__ int sOff[EP_NPB + 1];
  int t = threadIdx.x;
  int f = t & 63, wvi = t >> 6;
  int d0b = blockIdx.x * EP_NPB;
  if (t <= EP_NPB) {
    int d = d0b + t;
    sOff[t] = (d < N_NODES) ? offs[d] : N_EDGES;
  }
  __syncthreads();
  int eS = sOff[0];
  int nE = sOff[EP_NPB] - eS;
  bool fit = (nE <= EP_CAP);
  if (fit) {
    for (int i = t; i < nE; i += 256) sIdx[i] = srcS64[eS + i];
  }
  __syncthreads();

  for (int i = 0; i < 7; ++i) {
    int nl = wvi * 7 + i;
    int d = d0b + nl;
    if (d >= N_NODES) break;
    int e0 = sOff[nl];
    int deg = sOff[nl + 1] - e0;
    float Ub = bf2f(Uarr[(size_t)d * 64 + f]);
    float sum = 0.f;
    int full = deg & ~7;
    int base = 0;
    if (fit) {
      int rel = e0 - eS;
      for (; base < full; base += 8) {
        u16 S[8];
#pragma unroll
        for (int k = 0; k < 8; ++k) {
          int s64 = sIdx[rel + base + k];
          S[k] = Sarr[(size_t)s64 + f];
        }
#pragma unroll
        for (int k = 0; k < 8; ++k) sum += fmaxf(bf2f(S[k]) + Ub, 0.f);
      }
      if (base < deg) {
        u16 S[8]; bool ok[8];
#pragma unroll
        for (int k = 0; k < 8; ++k) {
          int j = base + k;
          ok[k] = j < deg;
          int s64 = sIdx[rel + (ok[k] ? j : 0)];
          S[k] = Sarr[(size_t)s64 + f];
        }
#pragma unroll
        for (int k = 0; k < 8; ++k) {
          float z = fmaxf(bf2f(S[k]) + Ub, 0.f);
          sum += ok[k] ? z : 0.f;
        }
      }
    } else {   // overflow fallback (statistically never: cap is ~75 sigma out)
      for (; base < full; base += 8) {
        u16 S[8];
#pragma unroll
        for (int k = 0; k < 8; ++k) {
          int s64 = srcS64[e0 + base + k];
          S[k] = Sarr[(size_t)s64 + f];
        }
#pragma unroll
        for (int k = 0; k < 8; ++k) sum += fmaxf(bf2f(S[k]) + Ub, 0.f);
      }
      if (base < deg) {
        u16 S[8]; bool ok[8];
#pragma unroll
        for (int k = 0; k < 8; ++k) {
          int j = base + k;
          ok[k] = j < deg;
          int s64 = srcS64[e0 + (ok[k] ? j : 0)];
          S[k] = Sarr[(size_t)s64 + f];
        }
#pragma unroll
        for (int k = 0; k < 8; ++k) {
          float z = fmaxf(bf2f(S[k]) + Ub, 0.f);
          sum += ok[k] ? z : 0.f;
        }
      }
    }
    aggH[(size_t)d * 64 + f] = f2bf(sum);
  }
}

// ---------------- node MLP (+ fused next-layer S'/U' GEMM, + fused decoder) --
__global__ __launch_bounds__(256) void node_kernel(
    const u16* __restrict__ h, const u16* __restrict__ aggH,
    const int* __restrict__ cnt,
    const u16* __restrict__ NB1T, const float* __restrict__ nb1,
    const float* __restrict__ bb2,
    const u16* __restrict__ M2T, const float* __restrict__ nb2,
    u16* __restrict__ h2, int layer,
    const u16* __restrict__ W1abT, const float* __restrict__ Wvx,
    const float* __restrict__ b1x, const float* __restrict__ pos,
    u16* __restrict__ Sarr, u16* __restrict__ Uarr,
    const float* __restrict__ dec_w, const float* __restrict__ dec_b,
    float* __restrict__ out) {
  __shared__ u16 Hs[64 * 72];
  __shared__ float sDeg[64];
  __shared__ float sPos[192];
  __shared__ float sRed[64][4];
  int t = threadIdx.x;
  int lane = t & 63, wvi = t >> 6;
  int n16 = lane & 15, quad = lane >> 4;
  int F = wvi * 16;
  int n0 = blockIdx.x * 64;

  if (t < 64) {
    int gn = n0 + t;
    sDeg[t] = (gn < N_NODES) ? (float)cnt[gn] : 0.f;
  }
  if (t >= 64 && t < 256) {
    int i = t - 64;
    int idx = n0 * 3 + i;
    sPos[i] = (idx < N_NODES * 3) ? pos[idx] : 0.f;
  }

  bf16x8 B1[4], B2[2];
  {
    const u16* p = NB1T + (size_t)(layer * 64 + F + n16) * 128 + quad * 8;
#pragma unroll
    for (int ks = 0; ks < 4; ++ks) B1[ks] = __builtin_bit_cast(bf16x8, *(const u16x8*)(p + ks * 32));
    const u16* q = M2T + (size_t)(layer * 64 + F + n16) * 64 + quad * 8;
#pragma unroll
    for (int ks = 0; ks < 2; ++ks) B2[ks] = __builtin_bit_cast(bf16x8, *(const u16x8*)(q + ks * 32));
  }
  float bias1 = nb1[layer * 64 + F + n16];
  float bb2f = bb2[layer * 64 + F + n16];
  float bias2 = nb2[layer * 64 + F + n16];
  __syncthreads();

  // GEMM1: [h|aggH] @ NB1T
  f32x4 acc[4];
#pragma unroll
  for (int m = 0; m < 4; ++m) acc[m] = (f32x4){0.f, 0.f, 0.f, 0.f};
#pragma unroll
  for (int m = 0; m < 4; ++m) {
    int row = n0 + m * 16 + n16;
    if (row >= N_NODES) row = N_NODES - 1;
    const u16* hp = h + (size_t)row * 64 + quad * 8;
    const u16* ap = aggH + (size_t)row * 64 + quad * 8;
    bf16x8 a0 = __builtin_bit_cast(bf16x8, *(const u16x8*)(hp));
    bf16x8 a1 = __builtin_bit_cast(bf16x8, *(const u16x8*)(hp + 32));
    bf16x8 a2 = __builtin_bit_cast(bf16x8, *(const u16x8*)(ap));
    bf16x8 a3 = __builtin_bit_cast(bf16x8, *(const u16x8*)(ap + 32));
    acc[m] = __builtin_amdgcn_mfma_f32_16x16x32_bf16(a0, B1[0], acc[m], 0, 0, 0);
    acc[m] = __builtin_amdgcn_mfma_f32_16x16x32_bf16(a1, B1[1], acc[m], 0, 0, 0);
    acc[m] = __builtin_amdgcn_mfma_f32_16x16x32_bf16(a2, B1[2], acc[m], 0, 0, 0);
    acc[m] = __builtin_amdgcn_mfma_f32_16x16x32_bf16(a3, B1[3], acc[m], 0, 0, 0);
  }
#pragma unroll
  for (int m = 0; m < 4; ++m)
#pragma unroll
    for (int r = 0; r < 4; ++r) {
      int e = m * 16 + quad * 4 + r;
      float v = acc[m][r] + bias1 + sDeg[e] * bb2f;
      v = v > 0.f ? v : 0.f;
      Hs[e * 72 + F + n16] = f2bf(v);
    }
  __syncthreads();

  // GEMM2: hidden @ M2T -> h2 (registers)
  float c2[4][4];
#pragma unroll
  for (int m = 0; m < 4; ++m) {
    const u16* hp = Hs + (m * 16 + n16) * 72 + quad * 8;
    f32x4 c = (f32x4){0.f, 0.f, 0.f, 0.f};
#pragma unroll
    for (int ks = 0; ks < 2; ++ks) {
      bf16x8 a = __builtin_bit_cast(bf16x8, *(const u16x8*)(hp + ks * 32));
      c = __builtin_amdgcn_mfma_f32_16x16x32_bf16(a, B2[ks], c, 0, 0, 0);
    }
#pragma unroll
    for (int r = 0; r < 4; ++r) c2[m][r] = c[r] + bias2;
  }
  __syncthreads();   // all Hs reads done

  // h2 tile -> LDS; global store only if another layer follows
#pragma unroll
  for (int m = 0; m < 4; ++m)
#pragma unroll
    for (int r = 0; r < 4; ++r) {
      int e = m * 16 + quad * 4 + r;
      u16 hv = f2bf(c2[m][r]);
      Hs[e * 72 + F + n16] = hv;
      int gn = n0 + e;
      if (layer < LAYERS - 1 && gn < N_NODES)
        h2[(size_t)gn * 64 + F + n16] = hv;
    }
  __syncthreads();

  if (layer < LAYERS - 1) {
    int lp = layer + 1;
    bf16x8 B3[2][2];
    float w0[2], w1[2], w2[2], bb[2]; bool isU[2];
#pragma unroll
    for (int nt = 0; nt < 2; ++nt) {
      int col = wvi * 32 + nt * 16 + n16;
      const u16* p = W1abT + (size_t)(lp * 128 + col) * 64 + quad * 8;
      B3[nt][0] = __builtin_bit_cast(bf16x8, *(const u16x8*)(p));
      B3[nt][1] = __builtin_bit_cast(bf16x8, *(const u16x8*)(p + 32));
      int f = col & 63; isU[nt] = col >= 64;
      w0[nt] = Wvx[(lp * 3 + 0) * 64 + f];
      w1[nt] = Wvx[(lp * 3 + 1) * 64 + f];
      w2[nt] = Wvx[(lp * 3 + 2) * 64 + f];
      bb[nt] = b1x[lp * 64 + f];
    }
    f32x4 a3[4][2];
#pragma unroll
    for (int m = 0; m < 4; ++m)
#pragma unroll
      for (int nt = 0; nt < 2; ++nt) a3[m][nt] = (f32x4){0.f, 0.f, 0.f, 0.f};
#pragma unroll
    for (int m = 0; m < 4; ++m) {
      const u16* hp = Hs + (m * 16 + n16) * 72 + quad * 8;
      bf16x8 a0 = __builtin_bit_cast(bf16x8, *(const u16x8*)(hp));
      bf16x8 a1 = __builtin_bit_cast(bf16x8, *(const u16x8*)(hp + 32));
#pragma unroll
      for (int nt = 0; nt < 2; ++nt) {
        a3[m][nt] = __builtin_amdgcn_mfma_f32_16x16x32_bf16(a0, B3[nt][0], a3[m][nt], 0, 0, 0);
        a3[m][nt] = __builtin_amdgcn_mfma_f32_16x16x32_bf16(a1, B3[nt][1], a3[m][nt], 0, 0, 0);
      }
    }
#pragma unroll
    for (int m = 0; m < 4; ++m)
#pragma unroll
      for (int nt = 0; nt < 2; ++nt) {
        int col = wvi * 32 + nt * 16 + n16;
        int f = col & 63;
#pragma unroll
        for (int r = 0; r < 4; ++r) {
          int e = m * 16 + quad * 4 + r;
          int grow = n0 + e;
          if (grow < N_NODES) {
            float P = sPos[e * 3] * w0[nt] + sPos[e * 3 + 1] * w1[nt] + sPos[e * 3 + 2] * w2[nt];
            if (!isU[nt]) Sarr[(size_t)grow * 64 + f] = f2bf(a3[m][nt][r] - P);
            else          Uarr[(size_t)grow * 64 + f] = f2bf(a3[m][nt][r] + P + bb[nt]);
          }
        }
      }
  } else {
    // fused decoder: out = h2 @ dec_w + dec_b
    int e = t >> 2, part = t & 3;
    float s = 0.f;
#pragma unroll
    for (int j = 0; j < 16; ++j)
      s += bf2f(Hs[e * 72 + part * 16 + j]) * dec_w[part * 16 + j];
    sRed[e][part] = s;
    __syncthreads();
    if (part == 0) {
      int gn = n0 + e;
      if (gn < N_NODES)
        out[gn] = sRed[e][0] + sRed[e][1] + sRed[e][2] + sRed[e][3] + dec_b[0];
    }
  }
}

extern "C" void kernel_launch(void* const* d_in, const int* in_sizes, int n_in,
                              void* d_out, int out_size, void* d_ws, size_t ws_size,
                              hipStream_t stream) {
  const float* node_pos   = (const float*)d_in[0];
  const float* node_feat  = (const float*)d_in[1];
  const int*   edge_index = (const int*)d_in[2];
  const float* enc_w      = (const float*)d_in[3];
  const float* enc_b      = (const float*)d_in[4];
  const float* edge_enc_w = (const float*)d_in[5];
  const float* edge_enc_b = (const float*)d_in[6];
  const float* ew1        = (const float*)d_in[7];
  const float* eb1        = (const float*)d_in[8];
  const float* ew2        = (const float*)d_in[9];
  const float* eb2        = (const float*)d_in[10];
  const float* nw1        = (const float*)d_in[11];
  const float* nb1        = (const float*)d_in[12];
  const float* nw2        = (const float*)d_in[13];
  const float* nb2        = (const float*)d_in[14];
  const float* dec_w      = (const float*)d_in[15];
  const float* dec_b      = (const float*)d_in[16];
  float* out = (float*)d_out;

  char* ws = (char*)d_ws;
  size_t off = 0;
  u16*    hA    = (u16*)(ws + off);    off += (size_t)N_NODES * 64 * 2;
  u16*    hB    = (u16*)(ws + off);    off += (size_t)N_NODES * 64 * 2;
  u16*    Sarr  = (u16*)(ws + off);    off += (size_t)N_NODES * 64 * 2;
  u16*    Uarr  = (u16*)(ws + off);    off += (size_t)N_NODES * 64 * 2;
  u16*    aggH  = (u16*)(ws + off);    off += (size_t)N_NODES * 64 * 2;
  u16*    W1abT = (u16*)(ws + off);    off += (size_t)LAYERS * 128 * 64 * 2;
  float*  Wvx   = (float*)(ws + off);  off += (size_t)LAYERS * 3 * 64 * 4;
  float*  b1x   = (float*)(ws + off);  off += (size_t)LAYERS * 64 * 4;
  u16*    NB1T  = (u16*)(ws + off);    off += (size_t)LAYERS * 64 * 128 * 2;
  float*  bb2   = (float*)(ws + off);  off += (size_t)LAYERS * 64 * 4;
  u16*    M2T   = (u16*)(ws + off);    off += (size_t)LAYERS * 64 * 64 * 2;
  int*    cnt      = (int*)(ws + off); off += (size_t)N_NODES * 4;
  int*    offsB    = (int*)(ws + off); off += (size_t)N_NODES * 4;
  int*    partials = (int*)(ws + off); off += 32 * 4;
  int*    rank     = (int*)(ws + off); off += (size_t)N_EDGES * 4;
  int*    srcS64   = (int*)(ws + off); off += (size_t)N_EDGES * 4;

  const int* dstA = edge_index + N_EDGES;
  const int NBLK = (N_NODES + 63) / 64;          // 782
  const int EP_GRID = (N_NODES + EP_NPB - 1) / EP_NPB;  // 1786

  init_kernel<<<1024, 256, 0, stream>>>(
      node_feat, enc_w, enc_b, ew1, eb1, ew2, eb2, nw1, nw2,
      edge_enc_w, edge_enc_b, hA, W1abT, Wvx, b1x, NB1T, bb2, M2T, cnt);

  // one-time CSR build (counting sort by dst, atomic-free scatter)
  hist_kernel<<<(N_EDGES + 255) / 256, 256, 0, stream>>>(dstA, cnt, rank);
  scan1_kernel<<<SCAN_NBLK, 256, 0, stream>>>(cnt, offsB, partials);
  scan3_kernel<<<(N_NODES + 255) / 256, 256, 0, stream>>>(offsB, partials);
  scatter_kernel<<<(N_EDGES + 255) / 256, 256, 0, stream>>>(edge_index, offsB, rank, srcS64);

  su_kernel<<<NBLK, 256, 0, stream>>>(hA, W1abT, Wvx, b1x, node_pos, Sarr, Uarr, 0);

  u16* hcur = hA; u16* hnext = hB;
  for (int l = 0; l < LAYERS; ++l) {
    ep_kernel<<<EP_GRID, 256, 0, stream>>>(Sarr, Uarr, srcS64, offsB, aggH);
    node_kernel<<<NBLK, 256, 0, stream>>>(hcur, aggH, cnt, NB1T, nb1, bb2, M2T, nb2,
                                          hnext, l, W1abT, Wvx, b1x, node_pos,
                                          Sarr, Uarr, dec_w, dec_b, out);
    u16* tmp = hcur; hcur = hnext; hnext = tmp;
  }
}